// Round 3
// baseline (416.264 us; speedup 1.0000x reference)
//
#include <hip/hip_runtime.h>

#define NCLS 80
#define NO 85
#define NT 200
#define BSZ 8
#define CIN 256
#define ANCHOR_T 2.91f
#define EPSF 1e-9f

// cells per level (BS*NA*ny*nx) and flat level bases
#define S0 153600
#define S1_ 38400
#define S2_ 9600
#define LB0 0
#define LB1 153600
#define LB2 192000

#define NGATH 1125
#define NHEAD 1050
#define NB (NGATH + NHEAD)   // 2175

// ws layout (bytes):
//   [tobj4 u32 x 201600 = 806400]  packed ((k+1)<<20)|(slot+1), atomicMax
//   [ctr u32 x 64 = 256]           [0..31] sub-done, [32] master-done, [33] record count
//   [headsp f32 x 1050]            per-head-block sum softplus(obj logit)
//   [gpart float4 x 1125]          per-gather-block {lbox_sum, n_valid, s1, s2}
//   [records int4 x 3072]          {cell idx, obj logit bits, t bits, 0}
#define WS_TOBJ_OFF 0
#define WS_CTR_OFF  806400
#define WS_HSP_OFF  806656
#define WS_GP_OFF   810880
#define WS_REC_OFF  828928
#define WS_ZERO_BYTES 806656

__device__ __constant__ float AW_[3] = {5.656854249f, 4.0f, 2.828427125f};
__device__ __constant__ float AH_[3] = {2.828427125f, 4.0f, 5.656854249f};

__device__ __forceinline__ float softplusf(float x) {
    return fmaxf(x, 0.0f) + log1pf(expf(-fabsf(x)));
}
__device__ __forceinline__ float sigmoidf_(float x) {
    return 1.0f / (1.0f + expf(-x));
}
__device__ __forceinline__ float wave_red(float v) {
    #pragma unroll
    for (int o = 32; o > 0; o >>= 1) v += __shfl_down(v, o);
    return v;
}

__global__ __launch_bounds__(256) void yolo_all(
    const float* __restrict__ f0, const float* __restrict__ w0, const float* __restrict__ b0,
    const float* __restrict__ f1, const float* __restrict__ w1, const float* __restrict__ b1,
    const float* __restrict__ f2, const float* __restrict__ w2, const float* __restrict__ b2,
    const float* __restrict__ targets,
    unsigned* __restrict__ tobj4, unsigned* __restrict__ ctr,
    float* __restrict__ hsp, float4* __restrict__ gp, int4* __restrict__ recs,
    float* __restrict__ out)
{
    const int bid = blockIdx.x;
    const int tid = threadIdx.x;

    __shared__ union __align__(16) {
        struct { float lw[3][CIN]; float part[16][16][13]; float ws_[4]; } h;
        struct {
            float lf[8][260];
            float pbox[8][4];
            float tbx[8][4];
            float px[8];
            int   vb[8], eb[8], ec[8], egi[8], egj[8], ek[8], rank[8];
            int   base, kloc;
            float r1[8], r2[8];
            float wsum[2][4];
        } g;
        struct { float red[24]; } fz;
    } sm;
    __shared__ int sm_last;

    if (bid < NGATH) {
        // ================= gathered entries =================
        int gid = bid;
        const int a = gid % 3;  gid /= 3;
        const int ntile = gid % 25; gid /= 25;
        const int o = gid % 5;
        const int l = gid / 5;
        const int nx = (l == 0) ? 80 : (l == 1) ? 40 : 20;
        const int ny = nx;
        const float* f  = (l == 0) ? f0 : (l == 1) ? f1 : f2;
        const float* w  = (l == 0) ? w0 : (l == 1) ? w1 : w2;
        const float* bi = (l == 0) ? b0 : (l == 1) ? b1 : b2;
        const int ltb   = (l == 0) ? LB0 : (l == 1) ? LB1 : LB2;

        if (tid < 8) {
            const int e = tid;
            const int n = ntile * 8 + e;
            const float* tg = targets + n * 6;
            float tb = tg[0], tcl = tg[1];
            float gx = tg[2] * (float)nx, gy = tg[3] * (float)ny;
            float gw = tg[4] * (float)nx, gh = tg[5] * (float)ny;
            float rw = gw / AW_[a], rh = gh / AH_[a];
            float mr = fmaxf(fmaxf(rw, 1.f / rw), fmaxf(rh, 1.f / rh));
            bool ma = mr < ANCHOR_T;
            float ox = 0.f, oy = 0.f;
            bool s = true;
            if (o == 1)      { s = (fmodf(gx, 1.f) < 0.5f) && (gx > 1.f); ox = 0.5f; }
            else if (o == 2) { s = (fmodf(gy, 1.f) < 0.5f) && (gy > 1.f); oy = 0.5f; }
            else if (o == 3) { float gxi = (float)nx - gx; s = (fmodf(gxi, 1.f) < 0.5f) && (gxi > 1.f); ox = -0.5f; }
            else if (o == 4) { float gyi = (float)ny - gy; s = (fmodf(gyi, 1.f) < 0.5f) && (gyi > 1.f); oy = -0.5f; }
            int valid = (ma && s) ? 1 : 0;
            sm.g.vb[e] = valid;
            if (valid) {
                int gi = (int)(gx - ox);
                int gj = (int)(gy - oy);
                sm.g.tbx[e][0] = gx - (float)gi;
                sm.g.tbx[e][1] = gy - (float)gj;
                sm.g.tbx[e][2] = gw;
                sm.g.tbx[e][3] = gh;
                sm.g.egi[e] = min(max(gi, 0), nx - 1);
                sm.g.egj[e] = min(max(gj, 0), ny - 1);
                sm.g.eb[e]  = (int)tb;
                sm.g.ec[e]  = (int)tcl;
                sm.g.ek[e]  = o * 600 + a * 200 + n;   // scatter-order key (last wins)
            }
        }
        __syncthreads();

        if (tid == 0) {
            int k = 0;
            #pragma unroll
            for (int e = 0; e < 8; ++e) { sm.g.rank[e] = k; k += sm.g.vb[e]; }
            sm.g.kloc = k;
            sm.g.base = (k > 0) ? (int)atomicAdd(&ctr[33], (unsigned)k) : 0;
        }
        __syncthreads();

        if (sm.g.kloc > 0) {
            // stage feature vectors (lane = channel; uncoalesced gather, L2/L3-served)
            #pragma unroll
            for (int e = 0; e < 8; ++e) {
                if (!sm.g.vb[e]) continue;
                sm.g.lf[e][tid] = f[((sm.g.eb[e] * CIN + tid) * ny + sm.g.egj[e]) * nx + sm.g.egi[e]];
            }
            __syncthreads();

            const int eg = tid >> 5;
            const int ol = tid & 31;
            float s1 = 0.f, s2 = 0.f;
            if (sm.g.vb[eg]) {
                const float4* lf4 = (const float4*)&sm.g.lf[eg][0];
                const int ecl = sm.g.ec[eg];
                #pragma unroll
                for (int ch = 0; ch < 3; ++ch) {
                    int oc = ch * 32 + ol;           // 0..84: box 0..3, obj 4, cls 5..84
                    if (oc < 85) {
                        int row = a * NO + oc;
                        const float4* wr4 = (const float4*)(w + row * CIN);
                        float dacc = 0.f;
                        #pragma unroll 8
                        for (int c4 = 0; c4 < 64; ++c4) {
                            float4 wv = wr4[c4];
                            float4 fv = lf4[c4];
                            dacc += wv.x * fv.x + wv.y * fv.y + wv.z * fv.z + wv.w * fv.w;
                        }
                        dacc += bi[row];
                        if (oc < 4)       sm.g.pbox[eg][oc] = dacc;
                        else if (oc == 4) sm.g.px[eg] = dacc;
                        else {
                            if ((oc - 5) == ecl) s1 += softplusf(-dacc);
                            else                 s2 += softplusf(dacc);
                        }
                    }
                }
            }
            s1 = wave_red(s1);
            s2 = wave_red(s2);
            __syncthreads();
            if ((tid & 63) == 0) { sm.g.wsum[0][tid >> 6] = s1; sm.g.wsum[1][tid >> 6] = s2; }
            __syncthreads();

            if (tid < 8) {
                if (sm.g.vb[tid]) {
                    const int e = tid;
                    float px = sigmoidf_(sm.g.pbox[e][0]) * 2.f - 0.5f;
                    float py = sigmoidf_(sm.g.pbox[e][1]) * 2.f - 0.5f;
                    float swp = sigmoidf_(sm.g.pbox[e][2]) * 2.f; float pw = swp * swp * AW_[a];
                    float shp = sigmoidf_(sm.g.pbox[e][3]) * 2.f; float ph = shp * shp * AH_[a];
                    float tx = sm.g.tbx[e][0], ty = sm.g.tbx[e][1], tw = sm.g.tbx[e][2], th = sm.g.tbx[e][3];
                    float b1x1 = px - pw * 0.5f, b1x2 = px + pw * 0.5f;
                    float b1y1 = py - ph * 0.5f, b1y2 = py + ph * 0.5f;
                    float b2x1 = tx - tw * 0.5f, b2x2 = tx + tw * 0.5f;
                    float b2y1 = ty - th * 0.5f, b2y2 = ty + th * 0.5f;
                    float iw = fmaxf(fminf(b1x2, b2x2) - fmaxf(b1x1, b2x1), 0.f);
                    float ih = fmaxf(fminf(b1y2, b2y2) - fmaxf(b1y1, b2y1), 0.f);
                    float inter = iw * ih;
                    float uni = pw * ph + tw * th - inter + EPSF;
                    float iou = inter / uni;
                    float cw = fmaxf(b1x2, b2x2) - fminf(b1x1, b2x1);
                    float chh = fmaxf(b1y2, b2y2) - fminf(b1y1, b2y1);
                    float c2 = cw * cw + chh * chh + EPSF;
                    float dx = b2x1 + b2x2 - b1x1 - b1x2;
                    float dy = b2y1 + b2y2 - b1y1 - b1y2;
                    float rho2 = (dx * dx + dy * dy) * 0.25f;
                    float dat = atanf(tw / (th + EPSF)) - atanf(pw / (ph + EPSF));
                    float v = 0.4052847346f * dat * dat;
                    float alpha = v / (v - iou + (1.f + EPSF));
                    float ciou = iou - (rho2 / c2 + v * alpha);
                    float t = fmaxf(ciou, 0.f);
                    int idx = ltb + ((sm.g.eb[e] * 3 + a) * ny + sm.g.egj[e]) * nx + sm.g.egi[e];
                    int slot = sm.g.base + sm.g.rank[e];
                    int4 r; r.x = idx; r.y = __float_as_int(sm.g.px[e]); r.z = __float_as_int(t); r.w = 0;
                    recs[slot] = r;
                    unsigned pk = ((unsigned)(sm.g.ek[e] + 1) << 20) | (unsigned)(slot + 1);
                    atomicMax(&tobj4[idx], pk);
                    sm.g.r1[tid] = 1.f - ciou;
                    sm.g.r2[tid] = 1.f;
                } else {
                    sm.g.r1[tid] = 0.f;
                    sm.g.r2[tid] = 0.f;
                }
            }
            __syncthreads();
            if (tid == 0) {
                float lb = 0.f, nv = 0.f;
                #pragma unroll
                for (int e = 0; e < 8; ++e) { lb += sm.g.r1[e]; nv += sm.g.r2[e]; }
                float4 gpv;
                gpv.x = lb; gpv.y = nv;
                gpv.z = sm.g.wsum[0][0] + sm.g.wsum[0][1] + sm.g.wsum[0][2] + sm.g.wsum[0][3];
                gpv.w = sm.g.wsum[1][0] + sm.g.wsum[1][1] + sm.g.wsum[1][2] + sm.g.wsum[1][3];
                gp[bid] = gpv;
            }
        } else {
            if (tid == 0) gp[bid] = make_float4(0.f, 0.f, 0.f, 0.f);
        }
    } else {
        // ================= objectness head (pure read; per-block slot result) =================
        const int hb = bid - NGATH;
        int l, blk0;
        if (hb < 800)       { l = 0; blk0 = 0; }
        else if (hb < 1000) { l = 1; blk0 = 800; }
        else                { l = 2; blk0 = 1000; }
        const int nx  = (l == 0) ? 80 : (l == 1) ? 40 : 20;
        const int ny  = nx;
        const int nxq = nx >> 2;
        const int perb = ny * nxq;
        const float* f  = (l == 0) ? f0 : (l == 1) ? f1 : f2;
        const float* w  = (l == 0) ? w0 : (l == 1) ? w1 : w2;
        const float* bi = (l == 0) ? b0 : (l == 1) ? b1 : b2;

        for (int i = tid; i < 3 * CIN; i += 256) {
            int a = i >> 8, c = i & 255;
            sm.h.lw[a][c] = w[(a * NO + 4) * CIN + c];
        }
        __syncthreads();

        const int chunk = tid >> 4;
        const int ql    = tid & 15;
        const int q     = (hb - blk0) * 16 + ql;
        const int b  = q / perb;
        const int r  = q - b * perb;
        const int y  = r / nxq;
        const int xq = r - y * nxq;

        const float4* f4 = (const float4*)f;
        const int c0 = chunk * 16;
        const int base = ((b * CIN + c0) * ny + y) * nxq + xq;

        float4 buf[16];
        #pragma unroll
        for (int i = 0; i < 16; ++i) buf[i] = f4[base + i * perb];

        float a0[12];
        #pragma unroll
        for (int j = 0; j < 12; ++j) a0[j] = 0.f;
        #pragma unroll
        for (int i = 0; i < 16; ++i) {
            float4 fv = buf[i];
            #pragma unroll
            for (int a = 0; a < 3; ++a) {
                float wv = sm.h.lw[a][c0 + i];
                a0[a*4+0] += fv.x * wv;
                a0[a*4+1] += fv.y * wv;
                a0[a*4+2] += fv.z * wv;
                a0[a*4+3] += fv.w * wv;
            }
        }
        #pragma unroll
        for (int v = 0; v < 12; ++v) sm.h.part[chunk][ql][v] = a0[v];
        __syncthreads();

        float sp = 0.f;
        if (tid < 192) {                       // 16 quads x 12 (a,j)
            int q2 = tid / 12, v = tid - q2 * 12;
            float s = 0.f;
            #pragma unroll
            for (int ch = 0; ch < 16; ++ch) s += sm.h.part[ch][q2][v];
            int a = v >> 2;
            s += bi[a * NO + 4];
            sp = softplusf(s);
        }
        sp = wave_red(sp);
        if ((tid & 63) == 0) sm.h.ws_[tid >> 6] = sp;
        __syncthreads();
        if (tid == 0)
            hsp[hb] = sm.h.ws_[0] + sm.h.ws_[1] + sm.h.ws_[2] + sm.h.ws_[3];
    }

    // ================= common tail: spread done-counters, last block finalizes =================
    __threadfence();
    if (tid == 0) {
        int rr = bid & 31;
        unsigned cnt = (rr < 31) ? 68u : 67u;          // NB = 2175 = 67*32 + 31
        unsigned old = atomicAdd(&ctr[rr], 1u);
        int lf = 0;
        if (old == cnt - 1u) {
            unsigned m = atomicAdd(&ctr[32], 1u);
            if (m == 31u) lf = 1;
        }
        sm_last = lf;
    }
    __syncthreads();
    if (!sm_last) return;

    __threadfence();
    if (tid < 24) sm.fz.red[tid] = 0.f;
    __syncthreads();

    // red[l*8+j]: 0 lbox_sum, 1 n_valid, 2 s1, 3 s2, 4 T2base, 5 T1, 6 T2sub, 7 fg
    {
        float t2b[3] = {0.f, 0.f, 0.f};
        for (int i = tid; i < NHEAD; i += 256) {
            int l = (i < 800) ? 0 : (i < 1000) ? 1 : 2;
            t2b[l] += hsp[i];
        }
        float lb[3] = {0,0,0}, nv[3] = {0,0,0}, c1[3] = {0,0,0}, c2[3] = {0,0,0};
        for (int i = tid; i < NGATH; i += 256) {
            int l = i / 375;
            float4 g = gp[i];
            lb[l] += g.x; nv[l] += g.y; c1[l] += g.z; c2[l] += g.w;
        }
        volatile unsigned* vctr = ctr;
        unsigned n = vctr[33];
        float T1[3] = {0,0,0}, T2s[3] = {0,0,0}, fgc[3] = {0,0,0};
        for (unsigned i = tid; i < n; i += 256) {
            int4 r = recs[i];
            unsigned old = atomicExch(&tobj4[r.x], 0u);       // dedupe: first taker wins
            if (old != 0u) {
                int ws_ = (int)(old & 0xFFFFFu) - 1;
                int4 wr = recs[ws_];
                float t = __int_as_float(wr.z);
                float x = __int_as_float(r.y);
                int l = (r.x >= LB2) ? 2 : (r.x >= LB1) ? 1 : 0;
                T1[l]  += t * softplusf(-x);
                T2s[l] += t * softplusf(x);
                fgc[l] += (t > 0.f) ? 1.f : 0.f;
            }
        }
        #pragma unroll
        for (int l = 0; l < 3; ++l) {
            if (lb[l] != 0.f)  atomicAdd(&sm.fz.red[l*8+0], lb[l]);
            if (nv[l] != 0.f)  atomicAdd(&sm.fz.red[l*8+1], nv[l]);
            if (c1[l] != 0.f)  atomicAdd(&sm.fz.red[l*8+2], c1[l]);
            if (c2[l] != 0.f)  atomicAdd(&sm.fz.red[l*8+3], c2[l]);
            if (t2b[l] != 0.f) atomicAdd(&sm.fz.red[l*8+4], t2b[l]);
            if (T1[l] != 0.f)  atomicAdd(&sm.fz.red[l*8+5], T1[l]);
            if (T2s[l] != 0.f) atomicAdd(&sm.fz.red[l*8+6], T2s[l]);
            if (fgc[l] != 0.f) atomicAdd(&sm.fz.red[l*8+7], fgc[l]);
        }
    }
    __syncthreads();
    if (tid == 0) {
        const float bal[3]   = {4.f, 1.f, 0.25f};
        const float numel[3] = {(float)S0, (float)S1_, (float)S2_};
        float lbox = 0.f, lobj = 0.f, lcls = 0.f;
        for (int i = 0; i < 3; ++i) {
            float lbs = sm.fz.red[i*8+0];
            float nv  = sm.fz.red[i*8+1];
            float s1  = sm.fz.red[i*8+2];
            float s2  = sm.fz.red[i*8+3];
            float T2b = sm.fz.red[i*8+4];
            float T1  = sm.fz.red[i*8+5];
            float T2  = T2b - sm.fz.red[i*8+6];
            float fg  = sm.fz.red[i*8+7];
            lbox += lbs / fmaxf(nv, 1.f);
            float pwc = nv * (float)(NCLS - 1) * 0.5f / fmaxf(nv, 2.f);
            lcls += (pwc * s1 + s2) / fmaxf(nv * (float)NCLS, 1.f);
            float bg = numel[i] - fg;
            float pwo = bg * 0.5f / fmaxf(fg, 2.f);
            lobj += (pwo * T1 + T2) / numel[i] * bal[i];
        }
        out[0] = lbox * 0.05f;
        out[1] = lobj * 1.0f;
        out[2] = lcls * 0.5f;
    }
}

extern "C" void kernel_launch(void* const* d_in, const int* in_sizes, int n_in,
                              void* d_out, int out_size, void* d_ws, size_t ws_size,
                              hipStream_t stream) {
    (void)in_sizes; (void)n_in; (void)out_size; (void)ws_size;
    const float* f0 = (const float*)d_in[0];
    const float* w0 = (const float*)d_in[1];
    const float* b0 = (const float*)d_in[2];
    const float* f1 = (const float*)d_in[3];
    const float* w1 = (const float*)d_in[4];
    const float* b1 = (const float*)d_in[5];
    const float* f2 = (const float*)d_in[6];
    const float* w2 = (const float*)d_in[7];
    const float* b2 = (const float*)d_in[8];
    const float* tg = (const float*)d_in[9];
    float* out = (float*)d_out;

    char* ws = (char*)d_ws;
    unsigned* tobj4 = (unsigned*)(ws + WS_TOBJ_OFF);
    unsigned* ctr   = (unsigned*)(ws + WS_CTR_OFF);
    float* hsp      = (float*)(ws + WS_HSP_OFF);
    float4* gp      = (float4*)(ws + WS_GP_OFF);
    int4* recs      = (int4*)(ws + WS_REC_OFF);

    hipMemsetAsync(d_ws, 0, WS_ZERO_BYTES, stream);
    yolo_all<<<dim3(NB), dim3(256), 0, stream>>>(f0, w0, b0, f1, w1, b1, f2, w2, b2, tg,
                                                 tobj4, ctr, hsp, gp, recs, out);
}

// Round 4
// 218.313 us; speedup vs baseline: 1.9067x; 1.9067x over previous
//
#include <hip/hip_runtime.h>

#define NCLS 80
#define NO 85
#define NT 200
#define BSZ 8
#define CIN 256
#define ANCHOR_T 2.91f
#define EPSF 1e-9f

// cells per level (BS*NA*ny*nx) and flat level bases
#define S0 153600
#define S1_ 38400
#define S2_ 9600
#define LB0 0
#define LB1 153600
#define LB2 192000

#define NHEAD 525    // 32 position-quads per block: L0 400, L1 100, L2 25
#define NGATH 1125
#define NB (NHEAD + NGATH)

// ws layout (bytes):
//   [tobj4 u32 x 201600 = 806400]   packed ((k+1)<<12)|(slot+1), atomicMax
//   [ctr u32 x 64 = 256]            [33] record count
//   [hsp f32 x 525 -> 2112 B]       per-head-block sum softplus(obj logit)
//   [gp float4 x 1125 = 18000]      per-gather-block {lbox_sum, n_valid, s1, s2}
//   [recs int4 x 3072 = 49152]      {cell idx, obj logit bits, t bits, 0}
#define WS_TOBJ_OFF 0
#define WS_CTR_OFF  806400
#define WS_HSP_OFF  806656
#define WS_GP_OFF   808768
#define WS_REC_OFF  826768
#define ZERO_QUADS  50416            // (806400+256)/16

__device__ __constant__ float AW_[3] = {5.656854249f, 4.0f, 2.828427125f};
__device__ __constant__ float AH_[3] = {2.828427125f, 4.0f, 5.656854249f};

__device__ __forceinline__ float softplusf(float x) {
    return fmaxf(x, 0.0f) + log1pf(expf(-fabsf(x)));
}
__device__ __forceinline__ float sigmoidf_(float x) {
    return 1.0f / (1.0f + expf(-x));
}
__device__ __forceinline__ float wave_red(float v) {
    #pragma unroll
    for (int o = 32; o > 0; o >>= 1) v += __shfl_down(v, o);
    return v;
}

__global__ __launch_bounds__(256) void yolo_zero(float4* __restrict__ p) {
    int i = blockIdx.x * 256 + threadIdx.x;
    if (i < ZERO_QUADS) p[i] = make_float4(0.f, 0.f, 0.f, 0.f);
}

__global__ __launch_bounds__(256, 2) void yolo_main(
    const float* __restrict__ f0, const float* __restrict__ w0, const float* __restrict__ b0,
    const float* __restrict__ f1, const float* __restrict__ w1, const float* __restrict__ b1,
    const float* __restrict__ f2, const float* __restrict__ w2, const float* __restrict__ b2,
    const float* __restrict__ targets,
    unsigned* __restrict__ tobj4, unsigned* __restrict__ ctr,
    float* __restrict__ hsp, float4* __restrict__ gp, int4* __restrict__ recs)
{
    const int bid = blockIdx.x;
    const int tid = threadIdx.x;

    __shared__ union __align__(16) {
        struct { float lw[3][CIN]; float part[8][32][13]; float ws_[4]; } h;  // 3072+13312+16
        struct {
            float lf[8][260];
            float pbox[8][4];
            float tbx[8][4];
            float px[8];
            int   vb[8], eb[8], ec[8], egi[8], egj[8], ek[8], rank[8];
            int   base, kloc;
            float r1[8], r2[8];
            float wsum[2][4];
        } g;
    } sm;

    if (bid < NHEAD) {
        // ============ objectness head: block = 32 quads x 256 ch, one level ============
        int l, blk0;
        if (bid < 400)      { l = 0; blk0 = 0; }
        else if (bid < 500) { l = 1; blk0 = 400; }
        else                { l = 2; blk0 = 500; }
        const int perb = (l == 0) ? 1600 : (l == 1) ? 400 : 100;   // float4 plane stride
        const float* f  = (l == 0) ? f0 : (l == 1) ? f1 : f2;
        const float* w  = (l == 0) ? w0 : (l == 1) ? w1 : w2;
        const float* bi = (l == 0) ? b0 : (l == 1) ? b1 : b2;

        // stage 3 objectness weight rows into LDS
        for (int i = tid; i < 3 * CIN; i += 256) {
            int a = i >> 8, c = i & 255;
            sm.h.lw[a][c] = w[(a * NO + 4) * CIN + c];
        }
        __syncthreads();

        const int q  = tid & 31;           // quad within block
        const int cg = tid >> 5;           // 8 channel groups of 32
        const int qL = (bid - blk0) * 32 + q;
        const int b  = qL / perb;
        const int r  = qL - b * perb;
        const int cbase = cg * 32;
        const float4* f4 = (const float4*)f;
        const int base = (b * CIN + cbase) * perb + r;

        float a0[12];
        #pragma unroll
        for (int j = 0; j < 12; ++j) a0[j] = 0.f;

        for (int i8 = 0; i8 < 4; ++i8) {
            float4 bf[8];
            #pragma unroll
            for (int u = 0; u < 8; ++u) bf[u] = f4[base + (i8 * 8 + u) * perb];
            #pragma unroll
            for (int u = 0; u < 8; ++u) {
                float4 fv = bf[u];
                int c = cbase + i8 * 8 + u;
                #pragma unroll
                for (int a = 0; a < 3; ++a) {
                    float wv = sm.h.lw[a][c];
                    a0[a*4+0] += fv.x * wv;
                    a0[a*4+1] += fv.y * wv;
                    a0[a*4+2] += fv.z * wv;
                    a0[a*4+3] += fv.w * wv;
                }
            }
        }
        #pragma unroll
        for (int v = 0; v < 12; ++v) sm.h.part[cg][q][v] = a0[v];
        __syncthreads();

        // epilogue: 32 quads x 12 (a,j) = 384 outputs; softplus-sum them
        float sp = 0.f;
        #pragma unroll
        for (int pass = 0; pass < 2; ++pass) {
            int u = tid + pass * 256;
            if (u < 384) {
                int q2 = u / 12, v = u - q2 * 12;
                float s = 0.f;
                #pragma unroll
                for (int cg2 = 0; cg2 < 8; ++cg2) s += sm.h.part[cg2][q2][v];
                s += bi[(v >> 2) * NO + 4];
                sp += softplusf(s);
            }
        }
        sp = wave_red(sp);
        if ((tid & 63) == 0) sm.h.ws_[tid >> 6] = sp;
        __syncthreads();
        if (tid == 0)
            hsp[bid] = sm.h.ws_[0] + sm.h.ws_[1] + sm.h.ws_[2] + sm.h.ws_[3];
        return;
    }

    // ================= gathered entries =================
    int gid = bid - NHEAD;
    const int gbid = gid;
    const int a = gid % 3;  gid /= 3;
    const int ntile = gid % 25; gid /= 25;
    const int o = gid % 5;
    const int l = gid / 5;
    const int nx = (l == 0) ? 80 : (l == 1) ? 40 : 20;
    const int ny = nx;
    const float* f  = (l == 0) ? f0 : (l == 1) ? f1 : f2;
    const float* w  = (l == 0) ? w0 : (l == 1) ? w1 : w2;
    const float* bi = (l == 0) ? b0 : (l == 1) ? b1 : b2;
    const int ltb   = (l == 0) ? LB0 : (l == 1) ? LB1 : LB2;

    if (tid < 8) {
        const int e = tid;
        const int n = ntile * 8 + e;
        const float* tg = targets + n * 6;
        float tb = tg[0], tcl = tg[1];
        float gx = tg[2] * (float)nx, gy = tg[3] * (float)ny;
        float gw = tg[4] * (float)nx, gh = tg[5] * (float)ny;
        float rw = gw / AW_[a], rh = gh / AH_[a];
        float mr = fmaxf(fmaxf(rw, 1.f / rw), fmaxf(rh, 1.f / rh));
        bool ma = mr < ANCHOR_T;
        float ox = 0.f, oy = 0.f;
        bool s = true;
        if (o == 1)      { s = (fmodf(gx, 1.f) < 0.5f) && (gx > 1.f); ox = 0.5f; }
        else if (o == 2) { s = (fmodf(gy, 1.f) < 0.5f) && (gy > 1.f); oy = 0.5f; }
        else if (o == 3) { float gxi = (float)nx - gx; s = (fmodf(gxi, 1.f) < 0.5f) && (gxi > 1.f); ox = -0.5f; }
        else if (o == 4) { float gyi = (float)ny - gy; s = (fmodf(gyi, 1.f) < 0.5f) && (gyi > 1.f); oy = -0.5f; }
        int valid = (ma && s) ? 1 : 0;
        sm.g.vb[e] = valid;
        if (valid) {
            int gi = (int)(gx - ox);
            int gj = (int)(gy - oy);
            sm.g.tbx[e][0] = gx - (float)gi;
            sm.g.tbx[e][1] = gy - (float)gj;
            sm.g.tbx[e][2] = gw;
            sm.g.tbx[e][3] = gh;
            sm.g.egi[e] = min(max(gi, 0), nx - 1);
            sm.g.egj[e] = min(max(gj, 0), ny - 1);
            sm.g.eb[e]  = (int)tb;
            sm.g.ec[e]  = (int)tcl;
            sm.g.ek[e]  = o * 600 + a * 200 + n;   // scatter-order key (last wins)
        }
    }
    __syncthreads();

    if (tid == 0) {
        int k = 0;
        #pragma unroll
        for (int e = 0; e < 8; ++e) { sm.g.rank[e] = k; k += sm.g.vb[e]; }
        sm.g.kloc = k;
        sm.g.base = (k > 0) ? (int)atomicAdd(&ctr[33], (unsigned)k) : 0;
    }
    __syncthreads();

    if (sm.g.kloc == 0) {
        if (tid == 0) gp[gbid] = make_float4(0.f, 0.f, 0.f, 0.f);
        return;
    }

    #pragma unroll
    for (int e = 0; e < 8; ++e) {
        if (!sm.g.vb[e]) continue;
        sm.g.lf[e][tid] = f[((sm.g.eb[e] * CIN + tid) * ny + sm.g.egj[e]) * nx + sm.g.egi[e]];
    }
    __syncthreads();

    const int eg = tid >> 5;
    const int ol = tid & 31;
    float s1 = 0.f, s2 = 0.f;
    if (sm.g.vb[eg]) {
        const float4* lf4 = (const float4*)&sm.g.lf[eg][0];
        const int ecl = sm.g.ec[eg];
        #pragma unroll
        for (int ch = 0; ch < 3; ++ch) {
            int oc = ch * 32 + ol;           // 0..84: box 0..3, obj 4, cls 5..84
            if (oc < 85) {
                int row = a * NO + oc;
                const float4* wr4 = (const float4*)(w + row * CIN);
                float dacc = 0.f;
                #pragma unroll 8
                for (int c4 = 0; c4 < 64; ++c4) {
                    float4 wv = wr4[c4];
                    float4 fv = lf4[c4];
                    dacc += wv.x * fv.x + wv.y * fv.y + wv.z * fv.z + wv.w * fv.w;
                }
                dacc += bi[row];
                if (oc < 4)       sm.g.pbox[eg][oc] = dacc;
                else if (oc == 4) sm.g.px[eg] = dacc;
                else {
                    if ((oc - 5) == ecl) s1 += softplusf(-dacc);
                    else                 s2 += softplusf(dacc);
                }
            }
        }
    }
    s1 = wave_red(s1);
    s2 = wave_red(s2);
    __syncthreads();
    if ((tid & 63) == 0) { sm.g.wsum[0][tid >> 6] = s1; sm.g.wsum[1][tid >> 6] = s2; }
    __syncthreads();

    if (tid < 8) {
        if (sm.g.vb[tid]) {
            const int e = tid;
            float px = sigmoidf_(sm.g.pbox[e][0]) * 2.f - 0.5f;
            float py = sigmoidf_(sm.g.pbox[e][1]) * 2.f - 0.5f;
            float swp = sigmoidf_(sm.g.pbox[e][2]) * 2.f; float pw = swp * swp * AW_[a];
            float shp = sigmoidf_(sm.g.pbox[e][3]) * 2.f; float ph = shp * shp * AH_[a];
            float tx = sm.g.tbx[e][0], ty = sm.g.tbx[e][1], tw = sm.g.tbx[e][2], th = sm.g.tbx[e][3];
            float b1x1 = px - pw * 0.5f, b1x2 = px + pw * 0.5f;
            float b1y1 = py - ph * 0.5f, b1y2 = py + ph * 0.5f;
            float b2x1 = tx - tw * 0.5f, b2x2 = tx + tw * 0.5f;
            float b2y1 = ty - th * 0.5f, b2y2 = ty + th * 0.5f;
            float iw = fmaxf(fminf(b1x2, b2x2) - fmaxf(b1x1, b2x1), 0.f);
            float ih = fmaxf(fminf(b1y2, b2y2) - fmaxf(b1y1, b2y1), 0.f);
            float inter = iw * ih;
            float uni = pw * ph + tw * th - inter + EPSF;
            float iou = inter / uni;
            float cw = fmaxf(b1x2, b2x2) - fminf(b1x1, b2x1);
            float chh = fmaxf(b1y2, b2y2) - fminf(b1y1, b2y1);
            float c2 = cw * cw + chh * chh + EPSF;
            float dx = b2x1 + b2x2 - b1x1 - b1x2;
            float dy = b2y1 + b2y2 - b1y1 - b1y2;
            float rho2 = (dx * dx + dy * dy) * 0.25f;
            float dat = atanf(tw / (th + EPSF)) - atanf(pw / (ph + EPSF));
            float v = 0.4052847346f * dat * dat;
            float alpha = v / (v - iou + (1.f + EPSF));
            float ciou = iou - (rho2 / c2 + v * alpha);
            float t = fmaxf(ciou, 0.f);
            int idx = ltb + ((sm.g.eb[e] * 3 + a) * ny + sm.g.egj[e]) * nx + sm.g.egi[e];
            int slot = sm.g.base + sm.g.rank[e];
            int4 rc; rc.x = idx; rc.y = __float_as_int(sm.g.px[e]); rc.z = __float_as_int(t); rc.w = 0;
            recs[slot] = rc;
            unsigned pk = ((unsigned)(sm.g.ek[e] + 1) << 12) | (unsigned)(slot + 1);
            atomicMax(&tobj4[idx], pk);
            sm.g.r1[tid] = 1.f - ciou;
            sm.g.r2[tid] = 1.f;
        } else {
            sm.g.r1[tid] = 0.f;
            sm.g.r2[tid] = 0.f;
        }
    }
    __syncthreads();
    if (tid == 0) {
        float lb = 0.f, nv = 0.f;
        #pragma unroll
        for (int e = 0; e < 8; ++e) { lb += sm.g.r1[e]; nv += sm.g.r2[e]; }
        float4 gpv;
        gpv.x = lb; gpv.y = nv;
        gpv.z = sm.g.wsum[0][0] + sm.g.wsum[0][1] + sm.g.wsum[0][2] + sm.g.wsum[0][3];
        gpv.w = sm.g.wsum[1][0] + sm.g.wsum[1][1] + sm.g.wsum[1][2] + sm.g.wsum[1][3];
        gp[gbid] = gpv;
    }
}

// single-block finalize (coherence via dispatch boundary, as in R2)
__global__ __launch_bounds__(1024) void yolo_fin(
    unsigned* __restrict__ tobj4, const unsigned* __restrict__ ctr,
    const float* __restrict__ hsp, const float4* __restrict__ gp,
    const int4* __restrict__ recs, float* __restrict__ out)
{
    const int tid = threadIdx.x;
    __shared__ float red[24];   // [l*8+j]: 0 lbox,1 nv,2 s1,3 s2,4 T2base,5 T1,6 T2sub,7 fg
    if (tid < 24) red[tid] = 0.f;
    __syncthreads();

    float t2b[3] = {0,0,0};
    for (int i = tid; i < NHEAD; i += 1024) {
        int l = (i < 400) ? 0 : (i < 500) ? 1 : 2;
        t2b[l] += hsp[i];
    }
    float lb[3] = {0,0,0}, nv[3] = {0,0,0}, c1[3] = {0,0,0}, c2[3] = {0,0,0};
    for (int i = tid; i < NGATH; i += 1024) {
        int l = i / 375;
        float4 g = gp[i];
        lb[l] += g.x; nv[l] += g.y; c1[l] += g.z; c2[l] += g.w;
    }
    const unsigned n = ctr[33];
    float T1[3] = {0,0,0}, T2s[3] = {0,0,0}, fgc[3] = {0,0,0};
    for (unsigned i = tid; i < n; i += 1024) {
        int4 r = recs[i];
        unsigned old = atomicExch(&tobj4[r.x], 0u);   // dedupe: first taker wins
        if (old != 0u) {
            int ws_ = (int)(old & 0xFFFu) - 1;
            float tw = __int_as_float(recs[ws_].z);
            float x  = __int_as_float(r.y);
            int l = (r.x >= LB2) ? 2 : (r.x >= LB1) ? 1 : 0;
            T1[l]  += tw * softplusf(-x);
            T2s[l] += tw * softplusf(x);
            fgc[l] += (tw > 0.f) ? 1.f : 0.f;
        }
    }
    #pragma unroll
    for (int l = 0; l < 3; ++l) {
        if (lb[l]  != 0.f) atomicAdd(&red[l*8+0], lb[l]);
        if (nv[l]  != 0.f) atomicAdd(&red[l*8+1], nv[l]);
        if (c1[l]  != 0.f) atomicAdd(&red[l*8+2], c1[l]);
        if (c2[l]  != 0.f) atomicAdd(&red[l*8+3], c2[l]);
        if (t2b[l] != 0.f) atomicAdd(&red[l*8+4], t2b[l]);
        if (T1[l]  != 0.f) atomicAdd(&red[l*8+5], T1[l]);
        if (T2s[l] != 0.f) atomicAdd(&red[l*8+6], T2s[l]);
        if (fgc[l] != 0.f) atomicAdd(&red[l*8+7], fgc[l]);
    }
    __syncthreads();
    if (tid == 0) {
        const float bal[3]   = {4.f, 1.f, 0.25f};
        const float numel[3] = {(float)S0, (float)S1_, (float)S2_};
        float lbox = 0.f, lobj = 0.f, lcls = 0.f;
        for (int i = 0; i < 3; ++i) {
            float lbs = red[i*8+0];
            float nvv = red[i*8+1];
            float s1  = red[i*8+2];
            float s2  = red[i*8+3];
            float T2b = red[i*8+4];
            float T1v = red[i*8+5];
            float T2  = T2b - red[i*8+6];
            float fg  = red[i*8+7];
            lbox += lbs / fmaxf(nvv, 1.f);
            float pwc = nvv * (float)(NCLS - 1) * 0.5f / fmaxf(nvv, 2.f);
            lcls += (pwc * s1 + s2) / fmaxf(nvv * (float)NCLS, 1.f);
            float bg = numel[i] - fg;
            float pwo = bg * 0.5f / fmaxf(fg, 2.f);
            lobj += (pwo * T1v + T2) / numel[i] * bal[i];
        }
        out[0] = lbox * 0.05f;
        out[1] = lobj * 1.0f;
        out[2] = lcls * 0.5f;
    }
}

extern "C" void kernel_launch(void* const* d_in, const int* in_sizes, int n_in,
                              void* d_out, int out_size, void* d_ws, size_t ws_size,
                              hipStream_t stream) {
    (void)in_sizes; (void)n_in; (void)out_size; (void)ws_size;
    const float* f0 = (const float*)d_in[0];
    const float* w0 = (const float*)d_in[1];
    const float* b0 = (const float*)d_in[2];
    const float* f1 = (const float*)d_in[3];
    const float* w1 = (const float*)d_in[4];
    const float* b1 = (const float*)d_in[5];
    const float* f2 = (const float*)d_in[6];
    const float* w2 = (const float*)d_in[7];
    const float* b2 = (const float*)d_in[8];
    const float* tg = (const float*)d_in[9];
    float* out = (float*)d_out;

    char* ws = (char*)d_ws;
    unsigned* tobj4 = (unsigned*)(ws + WS_TOBJ_OFF);
    unsigned* ctr   = (unsigned*)(ws + WS_CTR_OFF);
    float* hsp      = (float*)(ws + WS_HSP_OFF);
    float4* gp      = (float4*)(ws + WS_GP_OFF);
    int4* recs      = (int4*)(ws + WS_REC_OFF);

    yolo_zero<<<dim3((ZERO_QUADS + 255) / 256), dim3(256), 0, stream>>>((float4*)d_ws);
    yolo_main<<<dim3(NB), dim3(256), 0, stream>>>(f0, w0, b0, f1, w1, b1, f2, w2, b2, tg,
                                                  tobj4, ctr, hsp, gp, recs);
    yolo_fin<<<dim3(1), dim3(1024), 0, stream>>>(tobj4, ctr, hsp, gp, recs, out);
}